// Round 6
// baseline (352.374 us; speedup 1.0000x reference)
//
#include <hip/hip_runtime.h>

#define B_ 4
#define C_ 256
#define D_ 128
#define N_ 4096

typedef unsigned short u16t;
typedef _Float16 f16t;
typedef f16t f16x8 __attribute__((ext_vector_type(8)));
typedef float f32x4 __attribute__((ext_vector_type(4)));

static __device__ __forceinline__ u16t f2h(float f) {
  f16t h = (f16t)f; u16t u; __builtin_memcpy(&u, &h, 2); return u;
}
static __device__ __forceinline__ float h2f(u16t u) {
  f16t h; __builtin_memcpy(&h, &u, 2); return (float)h;
}

// ---------------- weight prep: cast fp32 weights to fp16, concat theta/phi ----------------
__global__ __launch_bounds__(256) void prep_w(const float* __restrict__ th_w,
                                              const float* __restrict__ ph_w,
                                              const float* __restrict__ th_b,
                                              const float* __restrict__ ph_b,
                                              const float* __restrict__ g_w,
                                              const float* __restrict__ w_w,
                                              u16t* __restrict__ Wc, u16t* __restrict__ gwc,
                                              u16t* __restrict__ wwc, float* __restrict__ bc) {
  const int idx = blockIdx.x * 256 + threadIdx.x;
  if (idx < 65536) {
    const int j = idx >> 8, c = idx & 255;
    const float v = (j < 128) ? th_w[j * 256 + c] : ph_w[(j - 128) * 256 + c];
    Wc[idx] = f2h(v);
  } else if (idx < 98304) {
    const int i = idx - 65536;
    gwc[i] = f2h(g_w[i]);
  } else if (idx < 131072) {
    const int i = idx - 98304;
    wwc[i] = f2h(w_w[i]);
  } else if (idx < 131328) {
    const int j = idx - 131072;
    bc[j] = (j < 128) ? th_b[j] : ph_b[j - 128];
  }
}

// ---------------- transpose + cast: x fp32 [B][C][N] -> xT fp16 [B][N][C] ----------------
__global__ __launch_bounds__(256) void transpose_x(const float* __restrict__ x,
                                                   u16t* __restrict__ xT) {
  __shared__ u16t t[32][33];
  const int b = blockIdx.z, c0 = blockIdx.y * 32, n0 = blockIdx.x * 32;
  const int tid = threadIdx.x;
  {
    const int cl = tid >> 3, n4 = (tid & 7) * 4;
    const float4 v = *(const float4*)(x + ((size_t)b * C_ + c0 + cl) * N_ + n0 + n4);
    t[n4 + 0][cl] = f2h(v.x);
    t[n4 + 1][cl] = f2h(v.y);
    t[n4 + 2][cl] = f2h(v.z);
    t[n4 + 3][cl] = f2h(v.w);
  }
  __syncthreads();
  {
    const int nl = tid >> 3, c4 = (tid & 7) * 4;
    unsigned int lo = (unsigned int)t[nl][c4 + 0] | ((unsigned int)t[nl][c4 + 1] << 16);
    unsigned int hi = (unsigned int)t[nl][c4 + 2] | ((unsigned int)t[nl][c4 + 3] << 16);
    uint2 o; o.x = lo; o.y = hi;
    *(uint2*)(xT + ((size_t)b * N_ + n0 + nl) * C_ + c0 + c4) = o;
  }
}

// ---------------- GEMM with register-prefetch pipeline ----------------
template<int COLBIAS, int STATS>
__global__ __launch_bounds__(256)
void gemm_bt(const u16t* __restrict__ Ab, long long aBS,
             const u16t* __restrict__ Bb, long long bBS,
             u16t* __restrict__ Cb, long long cBS, int ldc,
             const float* __restrict__ bias, float* __restrict__ stats, int K) {
  __shared__ __attribute__((aligned(16))) u16t lA[128 * 40];
  __shared__ __attribute__((aligned(16))) u16t lB[128 * 40];
  const int z = blockIdx.z;
  const u16t* A = Ab + (size_t)z * aBS;
  const u16t* B = Bb + (size_t)z * bBS;
  const int m0 = blockIdx.y * 128, j0 = blockIdx.x * 128;
  const int tid = threadIdx.x, lane = tid & 63, wave = tid >> 6;
  const int quad = lane >> 4, l16 = lane & 15;
  const int wm = wave & 1, wj = wave >> 1;
  const int srow = tid >> 2, ssg = tid & 3;    // staging row/segment (chunk 0)

  const f32x4 zero = {0.f, 0.f, 0.f, 0.f};
  f32x4 acc[4][4];
#pragma unroll
  for (int mi = 0; mi < 4; ++mi)
#pragma unroll
    for (int ji = 0; ji < 4; ++ji) acc[mi][ji] = zero;

  uint4 areg[2], breg[2];
#pragma unroll
  for (int rr = 0; rr < 2; ++rr) {
    const int row = rr * 64 + srow;
    areg[rr] = *(const uint4*)(A + (size_t)(m0 + row) * K + ssg * 8);
    breg[rr] = *(const uint4*)(B + (size_t)(j0 + row) * K + ssg * 8);
  }

  for (int k0 = 0; k0 < K; k0 += 32) {
#pragma unroll
    for (int rr = 0; rr < 2; ++rr) {
      const int row = rr * 64 + srow;
      *(uint4*)&lA[row * 40 + ssg * 8] = areg[rr];
      *(uint4*)&lB[row * 40 + ssg * 8] = breg[rr];
    }
    __syncthreads();
    if (k0 + 32 < K) {
#pragma unroll
      for (int rr = 0; rr < 2; ++rr) {
        const int row = rr * 64 + srow;
        areg[rr] = *(const uint4*)(A + (size_t)(m0 + row) * K + k0 + 32 + ssg * 8);
        breg[rr] = *(const uint4*)(B + (size_t)(j0 + row) * K + k0 + 32 + ssg * 8);
      }
    }
    f16x8 af[4], bfr[4];
#pragma unroll
    for (int i = 0; i < 4; ++i)
      af[i] = *(const f16x8*)&lA[(wm * 64 + i * 16 + l16) * 40 + quad * 8];
#pragma unroll
    for (int i = 0; i < 4; ++i)
      bfr[i] = *(const f16x8*)&lB[(wj * 64 + i * 16 + l16) * 40 + quad * 8];
#pragma unroll
    for (int mi = 0; mi < 4; ++mi)
#pragma unroll
      for (int ji = 0; ji < 4; ++ji)
        acc[mi][ji] = __builtin_amdgcn_mfma_f32_16x16x32_f16(af[mi], bfr[ji], acc[mi][ji], 0, 0, 0);
    __syncthreads();
  }

  float cb[4];
  if (COLBIAS) {
#pragma unroll
    for (int ji = 0; ji < 4; ++ji) cb[ji] = bias[j0 + wj * 64 + ji * 16 + l16];
  }
#pragma unroll
  for (int mi = 0; mi < 4; ++mi) {
#pragma unroll
    for (int r = 0; r < 4; ++r) {
      const int row = m0 + wm * 64 + mi * 16 + quad * 4 + r;
      const float rb = COLBIAS ? 0.f : bias[row];
      float s1 = 0.f, s2 = 0.f;
#pragma unroll
      for (int ji = 0; ji < 4; ++ji) {
        const int col = j0 + wj * 64 + ji * 16 + l16;
        float v = acc[mi][ji][r] + (COLBIAS ? cb[ji] : rb);
        Cb[(size_t)z * cBS + (size_t)row * ldc + col] = f2h(v);
        s1 += v; s2 += v * v;
      }
      if (STATS) {
        s1 += __shfl_xor(s1, 1); s1 += __shfl_xor(s1, 2);
        s1 += __shfl_xor(s1, 4); s1 += __shfl_xor(s1, 8);
        s2 += __shfl_xor(s2, 1); s2 += __shfl_xor(s2, 2);
        s2 += __shfl_xor(s2, 4); s2 += __shfl_xor(s2, 8);
        if (l16 == 0) {
          atomicAdd(&stats[row], s1);
          atomicAdd(&stats[256 + row], s2);
        }
      }
    }
  }
}

// ---------------- flash attention: KV-tile 128, register-prefetch pipeline ----------------
// QK [B][N][256] (Q cols 0..127, K cols 128..255), V [B][128][N], Y [B][N][128], all fp16
__global__ __launch_bounds__(256)
void attn(const u16t* __restrict__ QK, const u16t* __restrict__ V, u16t* __restrict__ Y) {
  const int b = blockIdx.y;
  const int n0 = blockIdx.x * 64;
  const int tid = threadIdx.x, lane = tid & 63, wave = tid >> 6;
  const int quad = lane >> 4, l16 = lane & 15;
  __shared__ __attribute__((aligned(16))) u16t Qs[64 * 136];
  __shared__ __attribute__((aligned(16))) u16t Ks[128 * 136];
  __shared__ __attribute__((aligned(16))) u16t Vs[128 * 136];
  __shared__ __attribute__((aligned(16))) u16t Ps[64 * 136];
  __shared__ float Sc[64];
  __shared__ float Ll[64];
  const u16t* QKb = QK + (size_t)b * N_ * 256;
  const u16t* Vb  = V  + (size_t)b * D_ * N_;
  const int crow = tid >> 4, csg = tid & 15;  // K/V staging: 16 rows x 16 segs per 256 thr

  // stage Q once (rows n0..n0+63, cols 0..127)
#pragma unroll
  for (int rr = 0; rr < 4; ++rr) {
    const int ch = rr * 256 + tid;
    const int row = ch >> 4, sg = ch & 15;
    *(uint4*)&Qs[row * 136 + sg * 8] = *(const uint4*)(QKb + (size_t)(n0 + row) * 256 + sg * 8);
  }

  // prologue: prefetch KV tile 0 into regs (K: 128x128, V: 128x128)
  uint4 kreg[8], vreg[8];
#pragma unroll
  for (int rr = 0; rr < 8; ++rr) {
    const int row = rr * 16 + crow;
    kreg[rr] = *(const uint4*)(QKb + (size_t)row * 256 + 128 + csg * 8);
    vreg[rr] = *(const uint4*)(Vb + (size_t)row * N_ + csg * 8);
  }

  const f32x4 zero = {0.f, 0.f, 0.f, 0.f};
  f32x4 o[4][2];
#pragma unroll
  for (int mi = 0; mi < 4; ++mi) { o[mi][0] = zero; o[mi][1] = zero; }
  float mrow[4] = {-1e30f, -1e30f, -1e30f, -1e30f};
  float lrow[4] = {0.f, 0.f, 0.f, 0.f};

  for (int kv = 0; kv < N_; kv += 128) {
    // commit prefetched tile to LDS
#pragma unroll
    for (int rr = 0; rr < 8; ++rr) {
      const int row = rr * 16 + crow;
      *(uint4*)&Ks[row * 136 + csg * 8] = kreg[rr];
      *(uint4*)&Vs[row * 136 + csg * 8] = vreg[rr];
    }
    __syncthreads();
    // issue next tile's loads (in flight during compute)
    if (kv + 128 < N_) {
#pragma unroll
      for (int rr = 0; rr < 8; ++rr) {
        const int row = rr * 16 + crow;
        kreg[rr] = *(const uint4*)(QKb + (size_t)(kv + 128 + row) * 256 + 128 + csg * 8);
        vreg[rr] = *(const uint4*)(Vb + (size_t)row * N_ + kv + 128 + csg * 8);
      }
    }

    // S = Q K^T : this wave's 16 rows x 128 cols
    f32x4 s[8];
#pragma unroll
    for (int ci = 0; ci < 8; ++ci) s[ci] = zero;
#pragma unroll
    for (int kc = 0; kc < 4; ++kc) {
      f16x8 a = *(const f16x8*)&Qs[(wave * 16 + l16) * 136 + (kc * 4 + quad) * 8];
#pragma unroll
      for (int ci = 0; ci < 8; ++ci) {
        f16x8 bb = *(const f16x8*)&Ks[(ci * 16 + l16) * 136 + (kc * 4 + quad) * 8];
        s[ci] = __builtin_amdgcn_mfma_f32_16x16x32_f16(a, bb, s[ci], 0, 0, 0);
      }
    }
    // online softmax for this wave's rows
#pragma unroll
    for (int r = 0; r < 4; ++r) {
      float mx = s[0][r];
#pragma unroll
      for (int ci = 1; ci < 8; ++ci) mx = fmaxf(mx, s[ci][r]);
      mx = fmaxf(mx, __shfl_xor(mx, 1)); mx = fmaxf(mx, __shfl_xor(mx, 2));
      mx = fmaxf(mx, __shfl_xor(mx, 4)); mx = fmaxf(mx, __shfl_xor(mx, 8));
      const float mnew = fmaxf(mrow[r], mx);
      const float sc = __expf(mrow[r] - mnew);
      const int prow = wave * 16 + quad * 4 + r;
      float psum = 0.f;
#pragma unroll
      for (int ci = 0; ci < 8; ++ci) {
        const u16t ph = f2h(__expf(s[ci][r] - mnew));
        psum += h2f(ph);
        Ps[prow * 136 + ci * 16 + l16] = ph;
      }
      lrow[r] = lrow[r] * sc + psum;
      mrow[r] = mnew;
      if (l16 == 0) Sc[prow] = sc;
    }
    __syncthreads();

    // rescale O, then O += P @ V : all 64 rows x this wave's 32 d-cols
#pragma unroll
    for (int mi = 0; mi < 4; ++mi) {
#pragma unroll
      for (int r = 0; r < 4; ++r) {
        const float scv = Sc[mi * 16 + quad * 4 + r];
        o[mi][0][r] *= scv;
        o[mi][1][r] *= scv;
      }
    }
#pragma unroll
    for (int kc = 0; kc < 4; ++kc) {
      f16x8 vb[2];
#pragma unroll
      for (int ci = 0; ci < 2; ++ci) {
        const int vrow = wave * 32 + ci * 16 + l16;
        vb[ci] = *(const f16x8*)&Vs[vrow * 136 + (kc * 4 + quad) * 8];
      }
#pragma unroll
      for (int mi = 0; mi < 4; ++mi) {
        f16x8 a = *(const f16x8*)&Ps[(mi * 16 + l16) * 136 + kc * 32 + quad * 8];
#pragma unroll
        for (int ci = 0; ci < 2; ++ci)
          o[mi][ci] = __builtin_amdgcn_mfma_f32_16x16x32_f16(a, vb[ci], o[mi][ci], 0, 0, 0);
      }
    }
    __syncthreads();
  }

  // final row-sum reduce and broadcast via LDS
#pragma unroll
  for (int r = 0; r < 4; ++r) {
    float s1 = lrow[r];
    s1 += __shfl_xor(s1, 1); s1 += __shfl_xor(s1, 2);
    s1 += __shfl_xor(s1, 4); s1 += __shfl_xor(s1, 8);
    if (l16 == 0) Ll[wave * 16 + quad * 4 + r] = s1;
  }
  __syncthreads();
#pragma unroll
  for (int mi = 0; mi < 4; ++mi) {
#pragma unroll
    for (int r = 0; r < 4; ++r) {
      const float inv = 1.0f / Ll[mi * 16 + quad * 4 + r];
      const int grow = n0 + mi * 16 + quad * 4 + r;
#pragma unroll
      for (int ci = 0; ci < 2; ++ci) {
        const int col = wave * 32 + ci * 16 + l16;
        Y[((size_t)b * N_ + grow) * D_ + col] = f2h(o[mi][ci][r] * inv);
      }
    }
  }
}

// ---------------- BN finalize + residual (fp32 in/out) ----------------
__global__ __launch_bounds__(256) void bn_fin(const u16t* __restrict__ wy,
                                              const float* __restrict__ x,
                                              const float* __restrict__ stats,
                                              const float* __restrict__ gamma,
                                              const float* __restrict__ beta,
                                              float* __restrict__ out) {
  const int b = blockIdx.z, c = blockIdx.y;
  const int n = blockIdx.x * 256 + threadIdx.x;
  const size_t off = ((size_t)b * C_ + c) * N_ + n;
  const float inv_n = 1.0f / 16384.0f;
  const float mean = stats[c] * inv_n;
  const float var = stats[256 + c] * inv_n - mean * mean;
  const float rs = rsqrtf(var + 1e-5f);
  const float g = gamma[c], bt = beta[c];
  out[off] = (h2f(wy[off]) - mean) * rs * g + bt + x[off];
}

// ---------------- launch ----------------
extern "C" void kernel_launch(void* const* d_in, const int* in_sizes, int n_in,
                              void* d_out, int out_size, void* d_ws, size_t ws_size,
                              hipStream_t stream) {
  const float* x     = (const float*)d_in[0];
  const float* g_w   = (const float*)d_in[1];
  const float* g_b   = (const float*)d_in[2];
  const float* th_w  = (const float*)d_in[3];
  const float* th_b  = (const float*)d_in[4];
  const float* ph_w  = (const float*)d_in[5];
  const float* ph_b  = (const float*)d_in[6];
  const float* w_w   = (const float*)d_in[7];
  const float* w_b   = (const float*)d_in[8];
  const float* gamma = (const float*)d_in[9];
  const float* beta  = (const float*)d_in[10];
  float* out = (float*)d_out;
  char* ws = (char*)d_ws;

  // Overlaid workspace (~21.2 MB peak), all internal tensors fp16:
  u16t* xT  = (u16t*)(ws);
  u16t* Y   = (u16t*)(ws);                  // overlays xT (xT dead after projections)
  u16t* QK  = (u16t*)(ws + 8388608);
  u16t* wy  = (u16t*)(ws + 8388608);        // overlays QK (QK dead after attn)
  u16t* V   = (u16t*)(ws + 16777216);
  u16t* Wc  = (u16t*)(ws + 20971520);
  u16t* gwc = (u16t*)(ws + 21102592);
  u16t* wwc = (u16t*)(ws + 21168128);
  float* bc = (float*)(ws + 21233664);
  float* stats = (float*)(ws + 21234688);

  hipMemsetAsync(stats, 0, 2048, stream);

  prep_w<<<dim3(513), dim3(256), 0, stream>>>(th_w, ph_w, th_b, ph_b, g_w, w_w,
                                              Wc, gwc, wwc, bc);
  transpose_x<<<dim3(128, 8, B_), dim3(256), 0, stream>>>(x, xT);

  // QK projection: [B,N,256] = xT[B,N,256c] @ Wc[256j,256c]^T + bc (col bias)
  gemm_bt<1, 0><<<dim3(2, 32, B_), dim3(256), 0, stream>>>(
      xT, (long long)N_ * C_, Wc, 0LL, QK, (long long)N_ * 256, 256,
      bc, (float*)nullptr, C_);
  // V projection: [B,128d,N] = gwc[128d,256c] @ xT[B,N,256c]^T + g_b (row bias)
  gemm_bt<0, 0><<<dim3(32, 1, B_), dim3(256), 0, stream>>>(
      gwc, 0LL, xT, (long long)N_ * C_, V, (long long)D_ * N_, N_,
      g_b, (float*)nullptr, C_);

  attn<<<dim3(64, B_), dim3(256), 0, stream>>>(QK, V, Y);

  // w_y: [B,256c,N] = wwc[256c,128d] @ Y[B,N,128d]^T + w_b (fp16 out + fp32 BN stats)
  gemm_bt<0, 1><<<dim3(32, 2, B_), dim3(256), 0, stream>>>(
      wwc, 0LL, Y, (long long)N_ * D_, wy, (long long)C_ * N_, N_,
      w_b, stats, D_);

  bn_fin<<<dim3(16, 256, B_), dim3(256), 0, stream>>>(wy, x, stats, gamma, beta, out);
}

// Round 7
// 257.432 us; speedup vs baseline: 1.3688x; 1.3688x over previous
//
#include <hip/hip_runtime.h>

#define B_ 4
#define C_ 256
#define D_ 128
#define N_ 4096
#define BN_ 16384   // B_*N_

typedef unsigned short u16t;
typedef _Float16 f16t;
typedef f16t f16x8 __attribute__((ext_vector_type(8)));
typedef float f32x4 __attribute__((ext_vector_type(4)));

static __device__ __forceinline__ u16t f2h(float f) {
  f16t h = (f16t)f; u16t u; __builtin_memcpy(&u, &h, 2); return u;
}
static __device__ __forceinline__ float h2f(u16t u) {
  f16t h; __builtin_memcpy(&h, &u, 2); return (float)h;
}

// ---------------- weight prep: cast fp32 weights to fp16, concat theta/phi ----------------
__global__ __launch_bounds__(256) void prep_w(const float* __restrict__ th_w,
                                              const float* __restrict__ ph_w,
                                              const float* __restrict__ th_b,
                                              const float* __restrict__ ph_b,
                                              const float* __restrict__ g_w,
                                              const float* __restrict__ w_w,
                                              u16t* __restrict__ Wc, u16t* __restrict__ gwc,
                                              u16t* __restrict__ wwc, float* __restrict__ bc) {
  const int idx = blockIdx.x * 256 + threadIdx.x;
  if (idx < 65536) {
    const int j = idx >> 8, c = idx & 255;
    const float v = (j < 128) ? th_w[j * 256 + c] : ph_w[(j - 128) * 256 + c];
    Wc[idx] = f2h(v);
  } else if (idx < 98304) {
    const int i = idx - 65536;
    gwc[i] = f2h(g_w[i]);
  } else if (idx < 131072) {
    const int i = idx - 98304;
    wwc[i] = f2h(w_w[i]);
  } else if (idx < 131328) {
    const int j = idx - 131072;
    bc[j] = (j < 128) ? th_b[j] : ph_b[j - 128];
  }
}

// ---------------- transpose + cast: x fp32 [B][C][N] -> xT fp16 [B][N][C] ----------------
__global__ __launch_bounds__(256) void transpose_x(const float* __restrict__ x,
                                                   u16t* __restrict__ xT) {
  __shared__ u16t t[32][33];
  const int b = blockIdx.z, c0 = blockIdx.y * 32, n0 = blockIdx.x * 32;
  const int tid = threadIdx.x;
  {
    const int cl = tid >> 3, n4 = (tid & 7) * 4;
    const float4 v = *(const float4*)(x + ((size_t)b * C_ + c0 + cl) * N_ + n0 + n4);
    t[n4 + 0][cl] = f2h(v.x);
    t[n4 + 1][cl] = f2h(v.y);
    t[n4 + 2][cl] = f2h(v.z);
    t[n4 + 3][cl] = f2h(v.w);
  }
  __syncthreads();
  {
    const int nl = tid >> 3, c4 = (tid & 7) * 4;
    unsigned int lo = (unsigned int)t[nl][c4 + 0] | ((unsigned int)t[nl][c4 + 1] << 16);
    unsigned int hi = (unsigned int)t[nl][c4 + 2] | ((unsigned int)t[nl][c4 + 3] << 16);
    uint2 o; o.x = lo; o.y = hi;
    *(uint2*)(xT + ((size_t)b * N_ + n0 + nl) * C_ + c0 + c4) = o;
  }
}

// ---------------- GEMM (round-3 form): C[m][j] = sum_k A[m][k]*B[j][k] ----------------
template<int COLBIAS, int STATS>
__global__ __launch_bounds__(256)
void gemm_bt(const u16t* __restrict__ Ab, long long aBS,
             const u16t* __restrict__ Bb, long long bBS,
             u16t* __restrict__ Cb, long long cBS, int ldc,
             const float* __restrict__ bias, float* __restrict__ stats, int K) {
  __shared__ __attribute__((aligned(16))) u16t lA[128 * 40];
  __shared__ __attribute__((aligned(16))) u16t lB[128 * 40];
  const int z = blockIdx.z;
  const u16t* A = Ab + (size_t)z * aBS;
  const u16t* B = Bb + (size_t)z * bBS;
  const int m0 = blockIdx.y * 128, j0 = blockIdx.x * 128;
  const int tid = threadIdx.x, lane = tid & 63, wave = tid >> 6;
  const int quad = lane >> 4, l16 = lane & 15;
  const int wm = wave & 1, wj = wave >> 1;

  const f32x4 zero = {0.f, 0.f, 0.f, 0.f};
  f32x4 acc[4][4];
#pragma unroll
  for (int mi = 0; mi < 4; ++mi)
#pragma unroll
    for (int ji = 0; ji < 4; ++ji) acc[mi][ji] = zero;

  for (int k0 = 0; k0 < K; k0 += 32) {
#pragma unroll
    for (int rr = 0; rr < 2; ++rr) {
      const int idx = rr * 256 + tid;
      const int row = idx >> 2, sg = idx & 3;
      *(uint4*)&lA[row * 40 + sg * 8] = *(const uint4*)(A + (size_t)(m0 + row) * K + k0 + sg * 8);
      *(uint4*)&lB[row * 40 + sg * 8] = *(const uint4*)(B + (size_t)(j0 + row) * K + k0 + sg * 8);
    }
    __syncthreads();
    f16x8 af[4], bfr[4];
#pragma unroll
    for (int i = 0; i < 4; ++i)
      af[i] = *(const f16x8*)&lA[(wm * 64 + i * 16 + l16) * 40 + quad * 8];
#pragma unroll
    for (int i = 0; i < 4; ++i)
      bfr[i] = *(const f16x8*)&lB[(wj * 64 + i * 16 + l16) * 40 + quad * 8];
#pragma unroll
    for (int mi = 0; mi < 4; ++mi)
#pragma unroll
      for (int ji = 0; ji < 4; ++ji)
        acc[mi][ji] = __builtin_amdgcn_mfma_f32_16x16x32_f16(af[mi], bfr[ji], acc[mi][ji], 0, 0, 0);
    __syncthreads();
  }

  float cb[4];
  if (COLBIAS) {
#pragma unroll
    for (int ji = 0; ji < 4; ++ji) cb[ji] = bias[j0 + wj * 64 + ji * 16 + l16];
  }
#pragma unroll
  for (int mi = 0; mi < 4; ++mi) {
#pragma unroll
    for (int r = 0; r < 4; ++r) {
      const int row = m0 + wm * 64 + mi * 16 + quad * 4 + r;
      const float rb = COLBIAS ? 0.f : bias[row];
      float s1 = 0.f, s2 = 0.f;
#pragma unroll
      for (int ji = 0; ji < 4; ++ji) {
        const int col = j0 + wj * 64 + ji * 16 + l16;
        float v = acc[mi][ji][r] + (COLBIAS ? cb[ji] : rb);
        Cb[(size_t)z * cBS + (size_t)row * ldc + col] = f2h(v);
        s1 += v; s2 += v * v;
      }
      if (STATS) {
        s1 += __shfl_xor(s1, 1); s1 += __shfl_xor(s1, 2);
        s1 += __shfl_xor(s1, 4); s1 += __shfl_xor(s1, 8);
        s2 += __shfl_xor(s2, 1); s2 += __shfl_xor(s2, 2);
        s2 += __shfl_xor(s2, 4); s2 += __shfl_xor(s2, 8);
        if (l16 == 0) {
          atomicAdd(&stats[row], s1);
          atomicAdd(&stats[256 + row], s2);
        }
      }
    }
  }
}

// ---------------- flash attention, KV-SPLIT x2 (round-3 body, half kv-range each) ----------
// QK [B][N][256] (Q cols 0..127, K cols 128..255), V [B][128][N]
// On [split][B][N][128] fp16 (per-split normalized O), ml [split][B*N][2] fp32 (m, l)
__global__ __launch_bounds__(256)
void attn(const u16t* __restrict__ QK, const u16t* __restrict__ V,
          u16t* __restrict__ On, float* __restrict__ ml) {
  const int b = blockIdx.y;
  const int split = blockIdx.z;
  const int n0 = blockIdx.x * 64;
  const int kv0 = split * (N_ / 2);
  const int tid = threadIdx.x, lane = tid & 63, wave = tid >> 6;
  const int quad = lane >> 4, l16 = lane & 15;
  __shared__ __attribute__((aligned(16))) u16t Qs[64 * 136];
  __shared__ __attribute__((aligned(16))) u16t Ks[64 * 136];
  __shared__ __attribute__((aligned(16))) u16t Vs[128 * 88];
  __shared__ __attribute__((aligned(16))) u16t Ps[64 * 72];
  __shared__ float Sc[64];
  __shared__ float Ll[64];
  const u16t* QKb = QK + (size_t)b * N_ * 256;
  const u16t* Vb  = V  + (size_t)b * D_ * N_;

  // stage Q once (rows n0..n0+63, cols 0..127)
#pragma unroll
  for (int rr = 0; rr < 4; ++rr) {
    const int ch = rr * 256 + tid;
    const int row = ch >> 4, sg = ch & 15;
    *(uint4*)&Qs[row * 136 + sg * 8] = *(const uint4*)(QKb + (size_t)(n0 + row) * 256 + sg * 8);
  }

  const f32x4 zero = {0.f, 0.f, 0.f, 0.f};
  f32x4 o[4][2];
#pragma unroll
  for (int mi = 0; mi < 4; ++mi) { o[mi][0] = zero; o[mi][1] = zero; }
  float mrow[4] = {-1e30f, -1e30f, -1e30f, -1e30f};
  float lrow[4] = {0.f, 0.f, 0.f, 0.f};

  for (int kv = kv0; kv < kv0 + N_ / 2; kv += 64) {
#pragma unroll
    for (int rr = 0; rr < 4; ++rr) {
      const int ch = rr * 256 + tid;
      const int row = ch >> 4, sg = ch & 15;
      *(uint4*)&Ks[row * 136 + sg * 8] =
          *(const uint4*)(QKb + (size_t)(kv + row) * 256 + 128 + sg * 8);
    }
#pragma unroll
    for (int rr = 0; rr < 4; ++rr) {
      const int ch = rr * 256 + tid;
      const int row = ch >> 3, sg = ch & 7;
      *(uint4*)&Vs[row * 88 + sg * 8] = *(const uint4*)(Vb + (size_t)row * N_ + kv + sg * 8);
    }
    __syncthreads();

    // S = Q K^T : this wave's 16 rows x 64 cols
    f32x4 s[4];
#pragma unroll
    for (int ci = 0; ci < 4; ++ci) s[ci] = zero;
#pragma unroll
    for (int kc = 0; kc < 4; ++kc) {
      f16x8 a = *(const f16x8*)&Qs[(wave * 16 + l16) * 136 + (kc * 4 + quad) * 8];
#pragma unroll
      for (int ci = 0; ci < 4; ++ci) {
        f16x8 bb = *(const f16x8*)&Ks[(ci * 16 + l16) * 136 + (kc * 4 + quad) * 8];
        s[ci] = __builtin_amdgcn_mfma_f32_16x16x32_f16(a, bb, s[ci], 0, 0, 0);
      }
    }
    // online softmax for this wave's rows
#pragma unroll
    for (int r = 0; r < 4; ++r) {
      float mx = s[0][r];
      mx = fmaxf(mx, s[1][r]); mx = fmaxf(mx, s[2][r]); mx = fmaxf(mx, s[3][r]);
      mx = fmaxf(mx, __shfl_xor(mx, 1)); mx = fmaxf(mx, __shfl_xor(mx, 2));
      mx = fmaxf(mx, __shfl_xor(mx, 4)); mx = fmaxf(mx, __shfl_xor(mx, 8));
      const float mnew = fmaxf(mrow[r], mx);
      const float sc = __expf(mrow[r] - mnew);
      const int prow = wave * 16 + quad * 4 + r;
      float psum = 0.f;
#pragma unroll
      for (int ci = 0; ci < 4; ++ci) {
        const u16t ph = f2h(__expf(s[ci][r] - mnew));
        psum += h2f(ph);
        Ps[prow * 72 + ci * 16 + l16] = ph;
      }
      lrow[r] = lrow[r] * sc + psum;
      mrow[r] = mnew;
      if (l16 == 0) Sc[prow] = sc;
    }
    __syncthreads();

    // rescale O, then O += P @ V : all 64 rows x this wave's 32 d-cols
#pragma unroll
    for (int mi = 0; mi < 4; ++mi) {
#pragma unroll
      for (int r = 0; r < 4; ++r) {
        const float scv = Sc[mi * 16 + quad * 4 + r];
        o[mi][0][r] *= scv;
        o[mi][1][r] *= scv;
      }
    }
#pragma unroll
    for (int kc = 0; kc < 2; ++kc) {
      f16x8 vb[2];
#pragma unroll
      for (int ci = 0; ci < 2; ++ci) {
        const int vrow = wave * 32 + ci * 16 + l16;
        vb[ci] = *(const f16x8*)&Vs[vrow * 88 + (kc * 4 + quad) * 8];
      }
#pragma unroll
      for (int mi = 0; mi < 4; ++mi) {
        f16x8 a = *(const f16x8*)&Ps[(mi * 16 + l16) * 72 + kc * 32 + quad * 8];
#pragma unroll
        for (int ci = 0; ci < 2; ++ci)
          o[mi][ci] = __builtin_amdgcn_mfma_f32_16x16x32_f16(a, vb[ci], o[mi][ci], 0, 0, 0);
      }
    }
    __syncthreads();
  }

  // final row-sum reduce; write (m, l) per row; broadcast l via LDS
#pragma unroll
  for (int r = 0; r < 4; ++r) {
    float s1 = lrow[r];
    s1 += __shfl_xor(s1, 1); s1 += __shfl_xor(s1, 2);
    s1 += __shfl_xor(s1, 4); s1 += __shfl_xor(s1, 8);
    if (l16 == 0) {
      const int prow = wave * 16 + quad * 4 + r;
      Ll[prow] = s1;
      float* mlp = ml + ((size_t)split * BN_ + (size_t)b * N_ + n0 + prow) * 2;
      mlp[0] = mrow[r]; mlp[1] = s1;
    }
  }
  __syncthreads();
#pragma unroll
  for (int mi = 0; mi < 4; ++mi) {
#pragma unroll
    for (int r = 0; r < 4; ++r) {
      const float inv = 1.0f / Ll[mi * 16 + quad * 4 + r];
      const int grow = n0 + mi * 16 + quad * 4 + r;
#pragma unroll
      for (int ci = 0; ci < 2; ++ci) {
        const int col = wave * 32 + ci * 16 + l16;
        On[(((size_t)split * B_ + b) * N_ + grow) * D_ + col] = f2h(o[mi][ci][r] * inv);
      }
    }
  }
}

// ---------------- combine the 2 kv-splits: Y = w0*O0n + w1*O1n (in-place over O0) -------
static __device__ __forceinline__ unsigned pk2(unsigned pa, unsigned pb, float w0, float w1) {
  const float lo = w0 * h2f((u16t)(pa & 0xffff)) + w1 * h2f((u16t)(pb & 0xffff));
  const float hi = w0 * h2f((u16t)(pa >> 16))    + w1 * h2f((u16t)(pb >> 16));
  return (unsigned)f2h(lo) | ((unsigned)f2h(hi) << 16);
}
__global__ __launch_bounds__(256) void attn_combine(u16t* __restrict__ O0,
                                                    const u16t* __restrict__ O1,
                                                    const float* __restrict__ ml) {
  const int idx = blockIdx.x * 256 + threadIdx.x;   // BN_*16 threads, 8 cols each
  const int row = idx >> 4, cg = idx & 15;
  const float m0 = ml[(size_t)row * 2], l0 = ml[(size_t)row * 2 + 1];
  const float m1 = ml[((size_t)BN_ + row) * 2], l1 = ml[((size_t)BN_ + row) * 2 + 1];
  const float m = fmaxf(m0, m1);
  float w0 = __expf(m0 - m) * l0, w1 = __expf(m1 - m) * l1;
  const float inv = 1.0f / (w0 + w1);
  w0 *= inv; w1 *= inv;
  const size_t off = (size_t)row * D_ + cg * 8;
  uint4 a = *(const uint4*)(O0 + off);
  uint4 b = *(const uint4*)(O1 + off);
  uint4 y;
  y.x = pk2(a.x, b.x, w0, w1);
  y.y = pk2(a.y, b.y, w0, w1);
  y.z = pk2(a.z, b.z, w0, w1);
  y.w = pk2(a.w, b.w, w0, w1);
  *(uint4*)(O0 + off) = y;
}

// ---------------- BN finalize + residual (fp32 in/out) ----------------
__global__ __launch_bounds__(256) void bn_fin(const u16t* __restrict__ wy,
                                              const float* __restrict__ x,
                                              const float* __restrict__ stats,
                                              const float* __restrict__ gamma,
                                              const float* __restrict__ beta,
                                              float* __restrict__ out) {
  const int b = blockIdx.z, c = blockIdx.y;
  const int n = blockIdx.x * 256 + threadIdx.x;
  const size_t off = ((size_t)b * C_ + c) * N_ + n;
  const float inv_n = 1.0f / 16384.0f;
  const float mean = stats[c] * inv_n;
  const float var = stats[256 + c] * inv_n - mean * mean;
  const float rs = rsqrtf(var + 1e-5f);
  const float g = gamma[c], bt = beta[c];
  out[off] = (h2f(wy[off]) - mean) * rs * g + bt + x[off];
}

// ---------------- launch ----------------
extern "C" void kernel_launch(void* const* d_in, const int* in_sizes, int n_in,
                              void* d_out, int out_size, void* d_ws, size_t ws_size,
                              hipStream_t stream) {
  const float* x     = (const float*)d_in[0];
  const float* g_w   = (const float*)d_in[1];
  const float* g_b   = (const float*)d_in[2];
  const float* th_w  = (const float*)d_in[3];
  const float* th_b  = (const float*)d_in[4];
  const float* ph_w  = (const float*)d_in[5];
  const float* ph_b  = (const float*)d_in[6];
  const float* w_w   = (const float*)d_in[7];
  const float* w_b   = (const float*)d_in[8];
  const float* gamma = (const float*)d_in[9];
  const float* beta  = (const float*)d_in[10];
  float* out = (float*)d_out;
  char* ws = (char*)d_ws;

  // Overlaid workspace (~21.5 MB peak), all internal tensors fp16:
  //   [0,       4.19M)  On split0 -> Y (combine in-place) ; was xT lower half
  //   [4.19M,   8.39M)  On split1                          ; was xT upper half
  //   [8.39M,  16.78M)  QK, later overwritten by wy
  //   [16.78M, 20.97M)  V
  //   [20.97M+ )        Wc, gwc, wwc, bc, stats, ml
  u16t* xT  = (u16t*)(ws);
  u16t* On  = (u16t*)(ws);                  // 2 splits, 4.19M each (over dead xT)
  u16t* Y   = (u16t*)(ws);                  // combine output, in-place over split0
  u16t* QK  = (u16t*)(ws + 8388608);
  u16t* wy  = (u16t*)(ws + 8388608);        // overlays QK (QK dead after attn)
  u16t* V   = (u16t*)(ws + 16777216);
  u16t* Wc  = (u16t*)(ws + 20971520);
  u16t* gwc = (u16t*)(ws + 21102592);
  u16t* wwc = (u16t*)(ws + 21168128);
  float* bc = (float*)(ws + 21233664);
  float* stats = (float*)(ws + 21234688);
  float* ml = (float*)(ws + 21236736);      // 2 * BN_ * 2 floats = 262144 B

  hipMemsetAsync(stats, 0, 2048, stream);

  prep_w<<<dim3(513), dim3(256), 0, stream>>>(th_w, ph_w, th_b, ph_b, g_w, w_w,
                                              Wc, gwc, wwc, bc);
  transpose_x<<<dim3(128, 8, B_), dim3(256), 0, stream>>>(x, xT);

  // QK projection: [B,N,256] = xT[B,N,256c] @ Wc[256j,256c]^T + bc (col bias)
  gemm_bt<1, 0><<<dim3(2, 32, B_), dim3(256), 0, stream>>>(
      xT, (long long)N_ * C_, Wc, 0LL, QK, (long long)N_ * 256, 256,
      bc, (float*)nullptr, C_);
  // V projection: [B,128d,N] = gwc[128d,256c] @ xT[B,N,256c]^T + g_b (row bias)
  gemm_bt<0, 0><<<dim3(32, 1, B_), dim3(256), 0, stream>>>(
      gwc, 0LL, xT, (long long)N_ * C_, V, (long long)D_ * N_, N_,
      g_b, (float*)nullptr, C_);

  attn<<<dim3(64, B_, 2), dim3(256), 0, stream>>>(QK, V, On, ml);
  attn_combine<<<dim3(1024), dim3(256), 0, stream>>>(
      (u16t*)ws, (u16t*)(ws + 4194304), ml);

  // w_y: [B,256c,N] = wwc[256c,128d] @ Y[B,N,128d]^T + w_b (fp16 out + fp32 BN stats)
  gemm_bt<0, 1><<<dim3(32, 2, B_), dim3(256), 0, stream>>>(
      wwc, 0LL, Y, (long long)N_ * D_, wy, (long long)C_ * N_, N_,
      w_b, stats, D_);

  bn_fin<<<dim3(16, 256, B_), dim3(256), 0, stream>>>(wy, x, stats, gamma, beta, out);
}

// Round 8
// 240.864 us; speedup vs baseline: 1.4630x; 1.0688x over previous
//
#include <hip/hip_runtime.h>

#define B_ 4
#define C_ 256
#define D_ 128
#define N_ 4096
#define BN_ 16384   // B_*N_

typedef unsigned short u16t;
typedef _Float16 f16t;
typedef f16t f16x8 __attribute__((ext_vector_type(8)));
typedef f16t f16x4 __attribute__((ext_vector_type(4)));
typedef float f32x4 __attribute__((ext_vector_type(4)));

static __device__ __forceinline__ u16t f2h(float f) {
  f16t h = (f16t)f; u16t u; __builtin_memcpy(&u, &h, 2); return u;
}
static __device__ __forceinline__ float h2f(u16t u) {
  f16t h; __builtin_memcpy(&h, &u, 2); return (float)h;
}

// ---------------- weight prep: cast fp32 weights to fp16, concat theta/phi ----------------
__global__ __launch_bounds__(256) void prep_w(const float* __restrict__ th_w,
                                              const float* __restrict__ ph_w,
                                              const float* __restrict__ th_b,
                                              const float* __restrict__ ph_b,
                                              const float* __restrict__ g_w,
                                              const float* __restrict__ w_w,
                                              u16t* __restrict__ Wc, u16t* __restrict__ gwc,
                                              u16t* __restrict__ wwc, float* __restrict__ bc) {
  const int idx = blockIdx.x * 256 + threadIdx.x;
  if (idx < 65536) {
    const int j = idx >> 8, c = idx & 255;
    const float v = (j < 128) ? th_w[j * 256 + c] : ph_w[(j - 128) * 256 + c];
    Wc[idx] = f2h(v);
  } else if (idx < 98304) {
    const int i = idx - 65536;
    gwc[i] = f2h(g_w[i]);
  } else if (idx < 131072) {
    const int i = idx - 98304;
    wwc[i] = f2h(w_w[i]);
  } else if (idx < 131328) {
    const int j = idx - 131072;
    bc[j] = (j < 128) ? th_b[j] : ph_b[j - 128];
  }
}

// ---------------- transpose + cast: x fp32 [B][C][N] -> xT fp16 [B][N][C] ----------------
__global__ __launch_bounds__(256) void transpose_x(const float* __restrict__ x,
                                                   u16t* __restrict__ xT) {
  __shared__ u16t t[32][33];
  const int b = blockIdx.z, c0 = blockIdx.y * 32, n0 = blockIdx.x * 32;
  const int tid = threadIdx.x;
  {
    const int cl = tid >> 3, n4 = (tid & 7) * 4;
    const float4 v = *(const float4*)(x + ((size_t)b * C_ + c0 + cl) * N_ + n0 + n4);
    t[n4 + 0][cl] = f2h(v.x);
    t[n4 + 1][cl] = f2h(v.y);
    t[n4 + 2][cl] = f2h(v.z);
    t[n4 + 3][cl] = f2h(v.w);
  }
  __syncthreads();
  {
    const int nl = tid >> 3, c4 = (tid & 7) * 4;
    unsigned int lo = (unsigned int)t[nl][c4 + 0] | ((unsigned int)t[nl][c4 + 1] << 16);
    unsigned int hi = (unsigned int)t[nl][c4 + 2] | ((unsigned int)t[nl][c4 + 3] << 16);
    uint2 o; o.x = lo; o.y = hi;
    *(uint2*)(xT + ((size_t)b * N_ + n0 + nl) * C_ + c0 + c4) = o;
  }
}

// ---------------- GEMM (round-3 form): C[m][j] = sum_k A[m][k]*B[j][k] ----------------
template<int COLBIAS, int STATS>
__global__ __launch_bounds__(256)
void gemm_bt(const u16t* __restrict__ Ab, long long aBS,
             const u16t* __restrict__ Bb, long long bBS,
             u16t* __restrict__ Cb, long long cBS, int ldc,
             const float* __restrict__ bias, float* __restrict__ stats, int K) {
  __shared__ __attribute__((aligned(16))) u16t lA[128 * 40];
  __shared__ __attribute__((aligned(16))) u16t lB[128 * 40];
  const int z = blockIdx.z;
  const u16t* A = Ab + (size_t)z * aBS;
  const u16t* B = Bb + (size_t)z * bBS;
  const int m0 = blockIdx.y * 128, j0 = blockIdx.x * 128;
  const int tid = threadIdx.x, lane = tid & 63, wave = tid >> 6;
  const int quad = lane >> 4, l16 = lane & 15;
  const int wm = wave & 1, wj = wave >> 1;

  const f32x4 zero = {0.f, 0.f, 0.f, 0.f};
  f32x4 acc[4][4];
#pragma unroll
  for (int mi = 0; mi < 4; ++mi)
#pragma unroll
    for (int ji = 0; ji < 4; ++ji) acc[mi][ji] = zero;

  for (int k0 = 0; k0 < K; k0 += 32) {
#pragma unroll
    for (int rr = 0; rr < 2; ++rr) {
      const int idx = rr * 256 + tid;
      const int row = idx >> 2, sg = idx & 3;
      *(uint4*)&lA[row * 40 + sg * 8] = *(const uint4*)(A + (size_t)(m0 + row) * K + k0 + sg * 8);
      *(uint4*)&lB[row * 40 + sg * 8] = *(const uint4*)(B + (size_t)(j0 + row) * K + k0 + sg * 8);
    }
    __syncthreads();
    f16x8 af[4], bfr[4];
#pragma unroll
    for (int i = 0; i < 4; ++i)
      af[i] = *(const f16x8*)&lA[(wm * 64 + i * 16 + l16) * 40 + quad * 8];
#pragma unroll
    for (int i = 0; i < 4; ++i)
      bfr[i] = *(const f16x8*)&lB[(wj * 64 + i * 16 + l16) * 40 + quad * 8];
#pragma unroll
    for (int mi = 0; mi < 4; ++mi)
#pragma unroll
      for (int ji = 0; ji < 4; ++ji)
        acc[mi][ji] = __builtin_amdgcn_mfma_f32_16x16x32_f16(af[mi], bfr[ji], acc[mi][ji], 0, 0, 0);
    __syncthreads();
  }

  float cb[4];
  if (COLBIAS) {
#pragma unroll
    for (int ji = 0; ji < 4; ++ji) cb[ji] = bias[j0 + wj * 64 + ji * 16 + l16];
  }
#pragma unroll
  for (int mi = 0; mi < 4; ++mi) {
#pragma unroll
    for (int r = 0; r < 4; ++r) {
      const int row = m0 + wm * 64 + mi * 16 + quad * 4 + r;
      const float rb = COLBIAS ? 0.f : bias[row];
      float s1 = 0.f, s2 = 0.f;
#pragma unroll
      for (int ji = 0; ji < 4; ++ji) {
        const int col = j0 + wj * 64 + ji * 16 + l16;
        float v = acc[mi][ji][r] + (COLBIAS ? cb[ji] : rb);
        Cb[(size_t)z * cBS + (size_t)row * ldc + col] = f2h(v);
        s1 += v; s2 += v * v;
      }
      if (STATS) {
        s1 += __shfl_xor(s1, 1); s1 += __shfl_xor(s1, 2);
        s1 += __shfl_xor(s1, 4); s1 += __shfl_xor(s1, 8);
        s2 += __shfl_xor(s2, 1); s2 += __shfl_xor(s2, 2);
        s2 += __shfl_xor(s2, 4); s2 += __shfl_xor(s2, 8);
        if (l16 == 0) {
          atomicAdd(&stats[row], s1);
          atomicAdd(&stats[256 + row], s2);
        }
      }
    }
  }
}

// ---------------- flash attention, S^T formulation, kv-split x4 ----------------
// Computes S^T = K Q^T so softmax + P.V are wave-local and register-resident:
// S^T acc: lane(l16,quad) reg r of acc[ci] = S^T[kv=ci*16+quad*4+r][q=wave*16+l16]
// -> exactly the B-operand layout of mfma_f32_16x16x16f16 (k = quad*4+j). No P LDS.
// QK [B][N][256] (Q cols 0..127, K cols 128..255), V [B][128][N]
// On [split][B][N][128] fp16 normalized, ml [split][B*N][2] fp32
__global__ __launch_bounds__(256)
void attn(const u16t* __restrict__ QK, const u16t* __restrict__ V,
          u16t* __restrict__ On0, u16t* __restrict__ On1, float* __restrict__ ml) {
  const int b = blockIdx.y;
  const int split = blockIdx.z;
  const int n0 = blockIdx.x * 64;
  const int kv0 = split * (N_ / 4);
  const int tid = threadIdx.x, lane = tid & 63, wave = tid >> 6;
  const int quad = lane >> 4, l16 = lane & 15;
  __shared__ __attribute__((aligned(16))) u16t Qs[64 * 136];
  __shared__ __attribute__((aligned(16))) u16t Ks[64 * 136];
  __shared__ __attribute__((aligned(16))) u16t Vs[128 * 72];   // 53.2 KB total -> 3 blocks/CU
  const u16t* QKb = QK + (size_t)b * N_ * 256;
  const u16t* Vb  = V  + (size_t)b * D_ * N_;

  // stage Q once (rows n0..n0+63, cols 0..127)
#pragma unroll
  for (int rr = 0; rr < 4; ++rr) {
    const int ch = rr * 256 + tid;
    const int row = ch >> 4, sg = ch & 15;
    *(uint4*)&Qs[row * 136 + sg * 8] = *(const uint4*)(QKb + (size_t)(n0 + row) * 256 + sg * 8);
  }

  const f32x4 zero = {0.f, 0.f, 0.f, 0.f};
  f32x4 o[8];
#pragma unroll
  for (int db = 0; db < 8; ++db) o[db] = zero;
  float m = -1e30f, l = 0.f;

  for (int kv = kv0; kv < kv0 + N_ / 4; kv += 64) {
#pragma unroll
    for (int rr = 0; rr < 4; ++rr) {
      const int ch = rr * 256 + tid;
      const int row = ch >> 4, sg = ch & 15;
      *(uint4*)&Ks[row * 136 + sg * 8] =
          *(const uint4*)(QKb + (size_t)(kv + row) * 256 + 128 + sg * 8);
    }
#pragma unroll
    for (int rr = 0; rr < 4; ++rr) {
      const int ch = rr * 256 + tid;
      const int row = ch >> 3, sg = ch & 7;
      *(uint4*)&Vs[row * 72 + sg * 8] = *(const uint4*)(Vb + (size_t)row * N_ + kv + sg * 8);
    }
    __syncthreads();

    // S^T = K Q^T : acc[ci] covers kv-block ci (rows), this wave's 16 q (cols)
    f32x4 s[4];
#pragma unroll
    for (int ci = 0; ci < 4; ++ci) s[ci] = zero;
#pragma unroll
    for (int kc = 0; kc < 4; ++kc) {
      f16x8 qf = *(const f16x8*)&Qs[(wave * 16 + l16) * 136 + (kc * 4 + quad) * 8];
#pragma unroll
      for (int ci = 0; ci < 4; ++ci) {
        f16x8 kf = *(const f16x8*)&Ks[(ci * 16 + l16) * 136 + (kc * 4 + quad) * 8];
        s[ci] = __builtin_amdgcn_mfma_f32_16x16x32_f16(kf, qf, s[ci], 0, 0, 0);
      }
    }

    // wave-local online softmax over this lane's q-column (16 kv values in-lane)
    float mx = s[0][0];
#pragma unroll
    for (int ci = 0; ci < 4; ++ci)
#pragma unroll
      for (int r = 0; r < 4; ++r) mx = fmaxf(mx, s[ci][r]);
    mx = fmaxf(mx, __shfl_xor(mx, 16));
    mx = fmaxf(mx, __shfl_xor(mx, 32));
    const float mnew = fmaxf(m, mx);
    const float al = __expf(m - mnew);
    float psum = 0.f;
    f16x4 pb[4];
#pragma unroll
    for (int ci = 0; ci < 4; ++ci) {
#pragma unroll
      for (int r = 0; r < 4; ++r) {
        const float p = __expf(s[ci][r] - mnew);
        psum += p;
        pb[ci][r] = (f16t)p;
      }
    }
    psum += __shfl_xor(psum, 16);
    psum += __shfl_xor(psum, 32);
    l = l * al + psum;
    m = mnew;

    // rescale O^T and accumulate O^T += V^T P^T (all register-resident)
#pragma unroll
    for (int db = 0; db < 8; ++db) {
#pragma unroll
      for (int r = 0; r < 4; ++r) o[db][r] *= al;
    }
#pragma unroll
    for (int ci = 0; ci < 4; ++ci) {
#pragma unroll
      for (int db = 0; db < 8; ++db) {
        f16x4 av = *(const f16x4*)&Vs[(db * 16 + l16) * 72 + ci * 16 + quad * 4];
        o[db] = __builtin_amdgcn_mfma_f32_16x16x16f16(av, pb[ci], o[db], 0, 0, 0);
      }
    }
    __syncthreads();
  }

  // epilogue: normalize by own l, store O^T (lane's q = wave*16+l16, d = db*16+quad*4+r)
  const int q = n0 + wave * 16 + l16;
  u16t* Onb = (split < 2) ? On0 : On1;
  const int sp = split & 1;
  const float inv = 1.0f / l;
  u16t* yrow = Onb + (((size_t)sp * B_ + b) * N_ + q) * D_;
#pragma unroll
  for (int db = 0; db < 8; ++db) {
    f16x4 pk;
#pragma unroll
    for (int r = 0; r < 4; ++r) pk[r] = (f16t)(o[db][r] * inv);
    *(f16x4*)(yrow + db * 16 + quad * 4) = pk;
  }
  if (quad == 0) {
    float* mlp = ml + ((size_t)split * BN_ + (size_t)b * N_ + q) * 2;
    mlp[0] = m; mlp[1] = l;
  }
}

// ---------------- combine the 4 kv-splits (in-place over split 0) ----------------
__global__ __launch_bounds__(256) void attn_combine(u16t* __restrict__ O0,
                                                    const u16t* __restrict__ O2,
                                                    const float* __restrict__ ml) {
  const int idx = blockIdx.x * 256 + threadIdx.x;   // BN_*16 threads, 8 cols each
  const int row = idx >> 4, cg = idx & 15;
  float mv[4], lv[4];
  float mstar = -1e30f;
#pragma unroll
  for (int s = 0; s < 4; ++s) {
    mv[s] = ml[((size_t)s * BN_ + row) * 2];
    lv[s] = ml[((size_t)s * BN_ + row) * 2 + 1];
    mstar = fmaxf(mstar, mv[s]);
  }
  float w[4], wsum = 0.f;
#pragma unroll
  for (int s = 0; s < 4; ++s) { w[s] = __expf(mv[s] - mstar) * lv[s]; wsum += w[s]; }
  const float inv = 1.0f / wsum;
#pragma unroll
  for (int s = 0; s < 4; ++s) w[s] *= inv;

  const size_t off = (size_t)row * D_ + cg * 8;
  const size_t half = (size_t)BN_ * D_;
  uint4 a0 = *(const uint4*)(O0 + off);
  uint4 a1 = *(const uint4*)(O0 + half + off);
  uint4 a2 = *(const uint4*)(O2 + off);
  uint4 a3 = *(const uint4*)(O2 + half + off);
  uint4 y;
  const unsigned* p0 = &a0.x; const unsigned* p1 = &a1.x;
  const unsigned* p2 = &a2.x; const unsigned* p3 = &a3.x;
  unsigned* py = &y.x;
#pragma unroll
  for (int i = 0; i < 4; ++i) {
    const float lo = w[0] * h2f((u16t)(p0[i] & 0xffff)) + w[1] * h2f((u16t)(p1[i] & 0xffff)) +
                     w[2] * h2f((u16t)(p2[i] & 0xffff)) + w[3] * h2f((u16t)(p3[i] & 0xffff));
    const float hi = w[0] * h2f((u16t)(p0[i] >> 16)) + w[1] * h2f((u16t)(p1[i] >> 16)) +
                     w[2] * h2f((u16t)(p2[i] >> 16)) + w[3] * h2f((u16t)(p3[i] >> 16));
    py[i] = (unsigned)f2h(lo) | ((unsigned)f2h(hi) << 16);
  }
  *(uint4*)(O0 + off) = y;
}

// ---------------- BN finalize + residual (fp32 in/out) ----------------
__global__ __launch_bounds__(256) void bn_fin(const u16t* __restrict__ wy,
                                              const float* __restrict__ x,
                                              const float* __restrict__ stats,
                                              const float* __restrict__ gamma,
                                              const float* __restrict__ beta,
                                              float* __restrict__ out) {
  const int b = blockIdx.z, c = blockIdx.y;
  const int n = blockIdx.x * 256 + threadIdx.x;
  const size_t off = ((size_t)b * C_ + c) * N_ + n;
  const float inv_n = 1.0f / 16384.0f;
  const float mean = stats[c] * inv_n;
  const float var = stats[256 + c] * inv_n - mean * mean;
  const float rs = rsqrtf(var + 1e-5f);
  const float g = gamma[c], bt = beta[c];
  out[off] = (h2f(wy[off]) - mean) * rs * g + bt + x[off];
}

// ---------------- launch ----------------
extern "C" void kernel_launch(void* const* d_in, const int* in_sizes, int n_in,
                              void* d_out, int out_size, void* d_ws, size_t ws_size,
                              hipStream_t stream) {
  const float* x     = (const float*)d_in[0];
  const float* g_w   = (const float*)d_in[1];
  const float* g_b   = (const float*)d_in[2];
  const float* th_w  = (const float*)d_in[3];
  const float* th_b  = (const float*)d_in[4];
  const float* ph_w  = (const float*)d_in[5];
  const float* ph_b  = (const float*)d_in[6];
  const float* w_w   = (const float*)d_in[7];
  const float* w_b   = (const float*)d_in[8];
  const float* gamma = (const float*)d_in[9];
  const float* beta  = (const float*)d_in[10];
  float* out = (float*)d_out;
  char* ws = (char*)d_ws;

  // Workspace (~21.8 MB peak):
  //   [0,       8.39M)  On splits 0,1 -> Y (combine in-place over split 0); was xT
  //   [8.39M,  16.78M)  QK, later overwritten by wy
  //   [16.78M, 20.97M)  V
  //   [20.97M+ )        Wc, gwc, wwc, bc, stats, ml (4 splits)
  // On splits 2,3 live in d_out (16.7MB fp32, dead until bn_fin overwrites it).
  u16t* xT  = (u16t*)(ws);
  u16t* Y   = (u16t*)(ws);                  // combine output, in-place over split0
  u16t* QK  = (u16t*)(ws + 8388608);
  u16t* wy  = (u16t*)(ws + 8388608);        // overlays QK (QK dead after attn)
  u16t* V   = (u16t*)(ws + 16777216);
  u16t* Wc  = (u16t*)(ws + 20971520);
  u16t* gwc = (u16t*)(ws + 21102592);
  u16t* wwc = (u16t*)(ws + 21168128);
  float* bc = (float*)(ws + 21233664);
  float* stats = (float*)(ws + 21234688);
  float* ml = (float*)(ws + 21236736);      // 4 * BN_ * 2 floats = 524288 B

  hipMemsetAsync(stats, 0, 2048, stream);

  prep_w<<<dim3(513), dim3(256), 0, stream>>>(th_w, ph_w, th_b, ph_b, g_w, w_w,
                                              Wc, gwc, wwc, bc);
  transpose_x<<<dim3(128, 8, B_), dim3(256), 0, stream>>>(x, xT);

  // QK projection: [B,N,256] = xT[B,N,256c] @ Wc[256j,256c]^T + bc (col bias)
  gemm_bt<1, 0><<<dim3(2, 32, B_), dim3(256), 0, stream>>>(
      xT, (long long)N_ * C_, Wc, 0LL, QK, (long long)N_ * 256, 256,
      bc, (float*)nullptr, C_);
  // V projection: [B,128d,N] = gwc[128d,256c] @ xT[B,N,256c]^T + g_b (row bias)
  gemm_bt<0, 0><<<dim3(32, 1, B_), dim3(256), 0, stream>>>(
      gwc, 0LL, xT, (long long)N_ * C_, V, (long long)D_ * N_, N_,
      g_b, (float*)nullptr, C_);

  attn<<<dim3(64, B_, 4), dim3(256), 0, stream>>>(QK, V, (u16t*)ws, (u16t*)d_out, ml);
  attn_combine<<<dim3(1024), dim3(256), 0, stream>>>((u16t*)ws, (u16t*)d_out, ml);

  // w_y: [B,256c,N] = wwc[256c,128d] @ Y[B,N,128d]^T + w_b (fp16 out + fp32 BN stats)
  gemm_bt<0, 1><<<dim3(32, 2, B_), dim3(256), 0, stream>>>(
      wwc, 0LL, Y, (long long)N_ * D_, wy, (long long)C_ * N_, N_,
      w_b, stats, D_);

  bn_fin<<<dim3(16, 256, B_), dim3(256), 0, stream>>>(wy, x, stats, gamma, beta, out);
}